// Round 1
// baseline (18405.829 us; speedup 1.0000x reference)
//
#include <hip/hip_runtime.h>
#include <math.h>

// DecoderTopDown beam-search decoder, f32 baseline (round 1).
// B=32 K=3 T=20 V=10000 R=36 E=512 VD=2048 H=1024 PH=256.
// Design notes:
//  - step-invariant vmean@Wi1[:,1024:3072] hoisted to gv1 (once per call)
//  - deterministic split-K f32 GEMM (no atomics: graph replays must be bit-stable)
//  - top-k replicates jax.lax.top_k tie-break (lower flat index wins ties)
//  - ws usage ~75 MB
#define BB 32
#define KB 3
#define TT 20
#define VV 10000
#define RR 36
#define ED 512
#define VD 2048
#define HH 1024
#define PH_ 256
#define ROWS 96
#define EOS_TOK 2

// ---------------- GEMM: C_part[s][m][n] = sum over this split's K-range of X[m,:]*W[n,:] ----------------
struct Seg { const float* X; const float* W; int ldx; int ldw; int koff; int klen; };
struct GemmA { Seg seg[3]; int nseg; int Mtot; int N; int Ktot; };

#define GBN 128
#define GKC 32

__global__ __launch_bounds__(128) void gemm_splitk(GemmA a, float* __restrict__ part) {
  __shared__ float Xs[96][GKC + 4];
  __shared__ float Ws[GBN][GKC + 4];
  const int tid = threadIdx.x;
  const int n0 = blockIdx.x * GBN;
  const int s = blockIdx.y;
  const int m0 = blockIdx.z * 96;
  const int S = gridDim.y;
  const int ck = (a.Ktot + S - 1) / S;
  const int ks = s * ck;
  const int ke = (a.Ktot < ks + ck) ? a.Ktot : (ks + ck);
  float acc[12][8];
#pragma unroll
  for (int r = 0; r < 12; ++r)
#pragma unroll
    for (int c = 0; c < 8; ++c) acc[r][c] = 0.f;
  const int tx = tid & 15, ty = tid >> 4;
  int segbase = 0;
  for (int sg = 0; sg < a.nseg; ++sg) {
    Seg sge = a.seg[sg];
    int lo = ks - segbase; if (lo < 0) lo = 0;
    int hi = ke - segbase; if (hi > sge.klen) hi = sge.klen;
    for (int k0 = lo; k0 < hi; k0 += GKC) {
      int kc = hi - k0; if (kc > GKC) kc = GKC;
      __syncthreads();
      for (int i = tid; i < 96 * GKC; i += 128) {
        int m = i >> 5, kk2 = i & 31;
        int mg = m0 + m;
        float v = 0.f;
        if (mg < a.Mtot && kk2 < kc) v = sge.X[(size_t)mg * sge.ldx + k0 + kk2];
        Xs[m][kk2] = v;
      }
      for (int i = tid; i < GBN * GKC; i += 128) {
        int n = i >> 5, kk2 = i & 31;
        int ng = n0 + n;
        float v = 0.f;
        if (ng < a.N && kk2 < kc) v = sge.W[(size_t)ng * sge.ldw + sge.koff + k0 + kk2];
        Ws[n][kk2] = v;
      }
      __syncthreads();
#pragma unroll
      for (int kq = 0; kq < GKC; kq += 4) {
        float4 xv[12];
#pragma unroll
        for (int r = 0; r < 12; ++r) xv[r] = *(const float4*)&Xs[ty * 12 + r][kq];
#pragma unroll
        for (int c = 0; c < 8; ++c) {
          float4 wv = *(const float4*)&Ws[tx + 16 * c][kq];
#pragma unroll
          for (int r = 0; r < 12; ++r) {
            acc[r][c] += xv[r].x * wv.x;
            acc[r][c] += xv[r].y * wv.y;
            acc[r][c] += xv[r].z * wv.z;
            acc[r][c] += xv[r].w * wv.w;
          }
        }
      }
    }
    segbase += sge.klen;
  }
#pragma unroll
  for (int r = 0; r < 12; ++r) {
    int mg = m0 + ty * 12 + r;
    if (mg >= a.Mtot) continue;
#pragma unroll
    for (int c = 0; c < 8; ++c) {
      int ng = n0 + tx + 16 * c;
      if (ng < a.N) part[((size_t)s * a.Mtot + mg) * a.N + ng] = acc[r][c];
    }
  }
}

// ---------------- small kernels ----------------
__global__ void init_kernel(float* h1s, float* c1s, float* h2s, float* c2s,
                            int* tok, float* lpt, int* fin, int* trj) {
  int idx = blockIdx.x * 256 + threadIdx.x;
  if (idx < ROWS * HH) { h1s[idx] = 0.f; c1s[idx] = 0.f; h2s[idx] = 0.f; c2s[idx] = 0.f; }
  if (idx < ROWS) { tok[idx] = 1; lpt[idx] = 0.f; fin[idx] = 0; }
  if (idx < ROWS * TT) trj[idx] = 0;
}

__global__ void vmean_kernel(const float* __restrict__ features, float* __restrict__ vme) {
  int idx = blockIdx.x * 256 + threadIdx.x;
  if (idx >= BB * VD) return;
  int b = idx / VD, d = idx - b * VD;
  float sum = 0.f;
  for (int r = 0; r < RR; ++r) sum += features[((size_t)b * RR + r) * VD + d];
  vme[idx] = sum / (float)RR;
}

__global__ void reduce_bias_kernel(float* __restrict__ out, const float* __restrict__ parts,
                                   const float* __restrict__ bias, int rows, int cols, int S) {
  int idx = blockIdx.x * 256 + threadIdx.x;
  if (idx >= rows * cols) return;
  int c = idx % cols;
  float acc = bias[c];
  for (int s = 0; s < S; ++s) acc += parts[(size_t)s * rows * cols + idx];
  out[idx] = acc;
}

__global__ void embed_kernel(const int* __restrict__ tok, const float* __restrict__ E,
                             float* __restrict__ emb) {
  int idx = blockIdx.x * 256 + threadIdx.x;
  if (idx >= ROWS * ED) return;
  int row = idx >> 9, e2 = idx & (ED - 1);
  emb[idx] = E[(size_t)tok[row] * ED + e2];
}

__global__ void lstm_kernel(const float* __restrict__ gP, int S,
                            const float* __restrict__ bias_col, const float* __restrict__ bias_row,
                            const float* __restrict__ c_in, float* __restrict__ h_out,
                            float* __restrict__ c_out) {
  int idx = blockIdx.x * 256 + threadIdx.x;
  if (idx >= ROWS * HH) return;
  int row = idx >> 10, j = idx & (HH - 1);
  int b = row / KB;
  float g[4];
#pragma unroll
  for (int gi = 0; gi < 4; ++gi) {
    float acc = bias_col ? bias_col[gi * HH + j] : bias_row[(size_t)b * 4 * HH + gi * HH + j];
    for (int s = 0; s < S; ++s) acc += gP[((size_t)s * ROWS + row) * (4 * HH) + gi * HH + j];
    g[gi] = acc;
  }
  float ig = 1.f / (1.f + expf(-g[0]));
  float fg = 1.f / (1.f + expf(-g[1]));
  float gg = tanhf(g[2]);
  float og = 1.f / (1.f + expf(-g[3]));
  float c = fg * c_in[idx] + ig * gg;
  h_out[idx] = og * tanhf(c);
  c_out[idx] = c;
}

__global__ __launch_bounds__(256) void attn_kernel(const float* __restrict__ hpP, int S,
    const float* __restrict__ bha, const float* __restrict__ featP,
    const float* __restrict__ features, const float* __restrict__ wa,
    float* __restrict__ vhat) {
  int row = blockIdx.x;
  int b = row / KB;
  int tid = threadIdx.x;
  __shared__ float hp[PH_];
  __shared__ float e[RR];
  {
    float v = bha[tid];
    for (int s = 0; s < S; ++s) v += hpP[((size_t)s * ROWS + row) * PH_ + tid];
    hp[tid] = v;
  }
  __syncthreads();
  int wv = tid >> 6, ln = tid & 63;
  for (int r = wv * 9; r < wv * 9 + 9; ++r) {
    float p = 0.f;
#pragma unroll
    for (int i = 0; i < 4; ++i) {
      int ph = ln * 4 + i;
      p += tanhf(featP[((size_t)b * RR + r) * PH_ + ph] + hp[ph]) * wa[ph];
    }
#pragma unroll
    for (int o = 32; o; o >>= 1) p += __shfl_down(p, o);
    if (ln == 0) e[r] = p;
  }
  __syncthreads();
  if (tid == 0) {
    float m = e[0];
    for (int r = 1; r < RR; ++r) m = fmaxf(m, e[r]);
    float se = 0.f;
    for (int r = 0; r < RR; ++r) se += expf(e[r] - m);
    for (int r = 0; r < RR; ++r) e[r] = expf(e[r] - m) / se;
  }
  __syncthreads();
  for (int d = tid; d < VD; d += 256) {
    float acc2 = 0.f;
    for (int r = 0; r < RR; ++r) acc2 += e[r] * features[((size_t)b * RR + r) * VD + d];
    vhat[(size_t)row * VD + d] = acc2;
  }
}

__device__ inline float wred_max(float v) {
#pragma unroll
  for (int o = 32; o; o >>= 1) v = fmaxf(v, __shfl_down(v, o));
  return v;
}
__device__ inline float wred_sum(float v) {
#pragma unroll
  for (int o = 32; o; o >>= 1) v += __shfl_down(v, o);
  return v;
}

__global__ __launch_bounds__(256) void logsm_kernel(const float* __restrict__ lP, int S,
    const float* __restrict__ bout, float* __restrict__ logits) {
  int row = blockIdx.x, tid = threadIdx.x;
  __shared__ float red[4];
  float m = -3.4e38f;
  for (int v = tid; v < VV; v += 256) {
    float acc = bout[v];
    for (int s = 0; s < S; ++s) acc += lP[((size_t)s * ROWS + row) * VV + v];
    logits[(size_t)row * VV + v] = acc;
    m = fmaxf(m, acc);
  }
  m = wred_max(m);
  if ((tid & 63) == 0) red[tid >> 6] = m;
  __syncthreads();
  m = fmaxf(fmaxf(red[0], red[1]), fmaxf(red[2], red[3]));
  __syncthreads();
  float se = 0.f;
  for (int v = tid; v < VV; v += 256) se += expf(logits[(size_t)row * VV + v] - m);
  se = wred_sum(se);
  if ((tid & 63) == 0) red[tid >> 6] = se;
  __syncthreads();
  se = red[0] + red[1] + red[2] + red[3];
  float l = logf(se);
  for (int v = tid; v < VV; v += 256) {
    size_t ix = (size_t)row * VV + v;
    logits[ix] = (logits[ix] - m) - l;
  }
}

__device__ inline bool better(float va, int ia, float vb, int ib) {
  if (va != vb) return va > vb;
  return (unsigned)ia < (unsigned)ib;
}

__global__ __launch_bounds__(256) void topk_kernel(const float* __restrict__ logp,
    const int* __restrict__ tok_old, const float* __restrict__ lpt_old,
    const int* __restrict__ fin_old, const int* __restrict__ trj_old, int t,
    int* __restrict__ tok_new, float* __restrict__ lpt_new, int* __restrict__ fin_new,
    int* __restrict__ trj_new, int* __restrict__ parent) {
  int b = blockIdx.x, tid = threadIdx.x;
  float lv[3] = {-INFINITY, -INFINITY, -INFINITY};
  int li[3] = {-1, -1, -1};
  float lpt_k[KB]; int fin_k[KB]; int tokp[KB];
#pragma unroll
  for (int k = 0; k < KB; ++k) {
    lpt_k[k] = lpt_old[b * KB + k];
    fin_k[k] = fin_old[b * KB + k];
    tokp[k] = tok_old[b * KB + k];
  }
  for (int i = tid; i < KB * VV; i += 256) {
    int k = i / VV, v = i - k * VV;
    if (t == 0 && k > 0) break;  // masked beams are exactly NEG; never in top-3
    float sc;
    if (fin_k[k]) {
      if (v != EOS_TOK) continue;  // lpt + (-1e9): never in top-3 (>=3 real candidates exist)
      sc = lpt_k[k];               // lpt + 0.0 exactly
    } else {
      float lg = logp[((size_t)(b * KB + k)) * VV + v];
      if (t > 0 && v == tokp[k]) lg -= 1e4f;  // same rounding order as reference
      sc = lpt_k[k] + lg;
    }
    if (better(sc, i, lv[2], li[2])) {
      if (better(sc, i, lv[1], li[1])) {
        lv[2] = lv[1]; li[2] = li[1];
        if (better(sc, i, lv[0], li[0])) { lv[1] = lv[0]; li[1] = li[0]; lv[0] = sc; li[0] = i; }
        else { lv[1] = sc; li[1] = i; }
      } else { lv[2] = sc; li[2] = i; }
    }
  }
  __shared__ float sv[256 * 3];
  __shared__ int si[256 * 3];
  sv[tid * 3 + 0] = lv[0]; sv[tid * 3 + 1] = lv[1]; sv[tid * 3 + 2] = lv[2];
  si[tid * 3 + 0] = li[0]; si[tid * 3 + 1] = li[1]; si[tid * 3 + 2] = li[2];
  for (int off = 128; off >= 1; off >>= 1) {
    __syncthreads();
    if (tid < off) {
      float av[3], bv2[3]; int ai3[3], bi3[3];
#pragma unroll
      for (int j = 0; j < 3; ++j) {
        av[j] = sv[tid * 3 + j]; ai3[j] = si[tid * 3 + j];
        bv2[j] = sv[(tid + off) * 3 + j]; bi3[j] = si[(tid + off) * 3 + j];
      }
      float mv[3]; int mi[3];
      int ai = 0, bi = 0;
#pragma unroll
      for (int o = 0; o < 3; ++o) {
        if (better(av[ai], ai3[ai], bv2[bi], bi3[bi])) { mv[o] = av[ai]; mi[o] = ai3[ai]; ++ai; }
        else { mv[o] = bv2[bi]; mi[o] = bi3[bi]; ++bi; }
      }
#pragma unroll
      for (int j = 0; j < 3; ++j) { sv[tid * 3 + j] = mv[j]; si[tid * 3 + j] = mi[j]; }
    }
  }
  __syncthreads();
  if (tid < KB) {
    float val = sv[tid];
    int idx = si[tid];
    int p = idx / VV, tk = idx - p * VV;
    parent[b * KB + tid] = p;
    tok_new[b * KB + tid] = tk;
    lpt_new[b * KB + tid] = val;
    fin_new[b * KB + tid] = fin_k[p] | (tk == EOS_TOK);
    for (int tt = 0; tt < TT; ++tt)
      trj_new[(b * KB + tid) * TT + tt] = (tt == t) ? tk : trj_old[(b * KB + p) * TT + tt];
  }
}

__global__ void gather_kernel(const int* __restrict__ parent,
    const float* __restrict__ h1p, const float* __restrict__ c1p,
    const float* __restrict__ h2p, const float* __restrict__ c2p,
    float* __restrict__ h1s, float* __restrict__ c1s,
    float* __restrict__ h2s, float* __restrict__ c2s) {
  int idx = blockIdx.x * 256 + threadIdx.x;
  if (idx >= ROWS * HH) return;
  int row = idx >> 10, j = idx & (HH - 1);
  int b = row / KB;
  int p = parent[row];
  size_t src = ((size_t)(b * KB + p) << 10) + j;
  h1s[idx] = h1p[src]; c1s[idx] = c1p[src];
  h2s[idx] = h2p[src]; c2s[idx] = c2p[src];
}

__global__ void out_kernel(const int* __restrict__ trj, const float* __restrict__ lpt,
                           float* __restrict__ out) {
  int idx = blockIdx.x * 256 + threadIdx.x;
  if (idx < BB * TT * KB) {
    int k = idx % KB;
    int rest = idx / KB;
    int t = rest % TT;
    int b = rest / TT;
    out[idx] = (float)trj[((size_t)(b * KB + k)) * TT + t];
  }
  if (idx < ROWS) out[BB * TT * KB + idx] = lpt[idx];
}

// ---------------- host ----------------
extern "C" void kernel_launch(void* const* d_in, const int* in_sizes, int n_in,
                              void* d_out, int out_size, void* d_ws, size_t ws_size,
                              hipStream_t stream) {
  const float* features = (const float*)d_in[0];
  const float* E = (const float*)d_in[1];
  const float* Wi1 = (const float*)d_in[2];
  const float* Wh1 = (const float*)d_in[3];
  const float* b1 = (const float*)d_in[4];
  const float* Wi2 = (const float*)d_in[5];
  const float* Wh2 = (const float*)d_in[6];
  const float* b2 = (const float*)d_in[7];
  const float* Wva = (const float*)d_in[8];
  const float* bva = (const float*)d_in[9];
  const float* Wha = (const float*)d_in[10];
  const float* bha = (const float*)d_in[11];
  const float* wa = (const float*)d_in[12];
  const float* Wout = (const float*)d_in[13];
  const float* bout = (const float*)d_in[14];
  float* out = (float*)d_out;

  const int SF = 4, SV2 = 4, SG = 16, SH = 16, SL = 8;
  float* base = (float*)d_ws;
  size_t off = 0;
  auto A = [&](size_t n) { float* p = base + off; off += n; return p; };
  float* featP = A((size_t)BB * RR * PH_);
  float* vme = A((size_t)BB * VD);
  float* gv1 = A((size_t)BB * 4 * HH);
  float* emb96 = A((size_t)ROWS * ED);
  float* vhat = A((size_t)ROWS * VD);
  float* logits = A((size_t)ROWS * VV);
  float* h1s = A((size_t)ROWS * HH);
  float* c1s = A((size_t)ROWS * HH);
  float* h2s = A((size_t)ROWS * HH);
  float* c2s = A((size_t)ROWS * HH);
  float* h1p = A((size_t)ROWS * HH);
  float* c1p = A((size_t)ROWS * HH);
  float* h2p = A((size_t)ROWS * HH);
  float* c2p = A((size_t)ROWS * HH);
  float* pF = A((size_t)SF * BB * RR * PH_);
  float* pV = A((size_t)SV2 * BB * 4 * HH);
  float* pG = A((size_t)SG * ROWS * 4 * HH);   // shared between LSTM1/LSTM2 gemms
  float* pH = A((size_t)SH * ROWS * PH_);
  float* pL = A((size_t)SL * ROWS * VV);
  float* lptA = A(ROWS);
  float* lptB = A(ROWS);
  int* ip = (int*)(base + off);
  int* tokA = ip; ip += ROWS;
  int* tokB = ip; ip += ROWS;
  int* finA = ip; ip += ROWS;
  int* finB = ip; ip += ROWS;
  int* par = ip; ip += ROWS;
  int* trjA = ip; ip += ROWS * TT;
  int* trjB = ip; ip += ROWS * TT;

  init_kernel<<<(ROWS * HH + 255) / 256, 256, 0, stream>>>(h1s, c1s, h2s, c2s, tokA, lptA, finA, trjA);
  vmean_kernel<<<(BB * VD + 255) / 256, 256, 0, stream>>>(features, vme);
  {
    GemmA a{};
    a.seg[0] = Seg{features, Wva, VD, VD, 0, VD};
    a.nseg = 1; a.Mtot = BB * RR; a.N = PH_; a.Ktot = VD;
    dim3 g((PH_ + GBN - 1) / GBN, SF, (BB * RR + 95) / 96);
    gemm_splitk<<<g, 128, 0, stream>>>(a, pF);
    reduce_bias_kernel<<<(BB * RR * PH_ + 255) / 256, 256, 0, stream>>>(featP, pF, bva, BB * RR, PH_, SF);
  }
  {
    GemmA a{};
    a.seg[0] = Seg{vme, Wi1, VD, 3584, 1024, VD};
    a.nseg = 1; a.Mtot = BB; a.N = 4 * HH; a.Ktot = VD;
    dim3 g((4 * HH + GBN - 1) / GBN, SV2, 1);
    gemm_splitk<<<g, 128, 0, stream>>>(a, pV);
    reduce_bias_kernel<<<(BB * 4 * HH + 255) / 256, 256, 0, stream>>>(gv1, pV, b1, BB, 4 * HH, SV2);
  }

  int *tokC = tokA, *tokN = tokB, *finC = finA, *finN = finB, *trjC = trjA, *trjN = trjB;
  float *lptC = lptA, *lptN = lptB;
  for (int t = 0; t < TT; ++t) {
    embed_kernel<<<(ROWS * ED + 255) / 256, 256, 0, stream>>>(tokC, E, emb96);
    {
      GemmA a{};
      a.seg[0] = Seg{h2s, Wi1, HH, 3584, 0, HH};
      a.seg[1] = Seg{emb96, Wi1, ED, 3584, 3072, ED};
      a.seg[2] = Seg{h1s, Wh1, HH, HH, 0, HH};
      a.nseg = 3; a.Mtot = ROWS; a.N = 4 * HH; a.Ktot = HH + ED + HH;
      dim3 g(32, SG, 1);
      gemm_splitk<<<g, 128, 0, stream>>>(a, pG);
    }
    lstm_kernel<<<(ROWS * HH + 255) / 256, 256, 0, stream>>>(pG, SG, nullptr, gv1, c1s, h1p, c1p);
    {
      GemmA a{};
      a.seg[0] = Seg{h1p, Wha, HH, HH, 0, HH};
      a.nseg = 1; a.Mtot = ROWS; a.N = PH_; a.Ktot = HH;
      dim3 g((PH_ + GBN - 1) / GBN, SH, 1);
      gemm_splitk<<<g, 128, 0, stream>>>(a, pH);
    }
    attn_kernel<<<ROWS, 256, 0, stream>>>(pH, SH, bha, featP, features, wa, vhat);
    {
      GemmA a{};
      a.seg[0] = Seg{h1p, Wi2, HH, 3072, 0, HH};
      a.seg[1] = Seg{vhat, Wi2, VD, 3072, 1024, VD};
      a.seg[2] = Seg{h2s, Wh2, HH, HH, 0, HH};
      a.nseg = 3; a.Mtot = ROWS; a.N = 4 * HH; a.Ktot = HH + VD + HH;
      dim3 g(32, SG, 1);
      gemm_splitk<<<g, 128, 0, stream>>>(a, pG);
    }
    lstm_kernel<<<(ROWS * HH + 255) / 256, 256, 0, stream>>>(pG, SG, b2, nullptr, c2s, h2p, c2p);
    {
      GemmA a{};
      a.seg[0] = Seg{h2p, Wout, HH, HH, 0, HH};
      a.nseg = 1; a.Mtot = ROWS; a.N = VV; a.Ktot = HH;
      dim3 g((VV + GBN - 1) / GBN, SL, 1);
      gemm_splitk<<<g, 128, 0, stream>>>(a, pL);
    }
    logsm_kernel<<<ROWS, 256, 0, stream>>>(pL, SL, bout, logits);
    topk_kernel<<<BB, 256, 0, stream>>>(logits, tokC, lptC, finC, trjC, t,
                                        tokN, lptN, finN, trjN, par);
    gather_kernel<<<(ROWS * HH + 255) / 256, 256, 0, stream>>>(par, h1p, c1p, h2p, c2p,
                                                               h1s, c1s, h2s, c2s);
    { int* tmp; float* tf;
      tmp = tokC; tokC = tokN; tokN = tmp;
      tmp = finC; finC = finN; finN = tmp;
      tmp = trjC; trjC = trjN; trjN = tmp;
      tf = lptC; lptC = lptN; lptN = tf; }
  }
  out_kernel<<<(BB * TT * KB + 255) / 256, 256, 0, stream>>>(trjC, lptC, out);
}

// Round 5
// 12236.816 us; speedup vs baseline: 1.5041x; 1.5041x over previous
//
#include <hip/hip_runtime.h>
#include <math.h>

// DecoderTopDown beam-search decoder, round 5: R1 passing source verbatim,
// with ONLY the gemm staging loops vectorized to float4 (batched independent
// loads -> LDS). FP accumulation chains bitwise identical to R1.
#define BB 32
#define KB 3
#define TT 20
#define VV 10000
#define RR 36
#define ED 512
#define VD 2048
#define HH 1024
#define PH_ 256
#define ROWS 96
#define EOS_TOK 2

// ---------------- GEMM: C_part[s][m][n] = sum over this split's K-range of X[m,:]*W[n,:] ----------------
struct Seg { const float* X; const float* W; int ldx; int ldw; int koff; int klen; };
struct GemmA { Seg seg[3]; int nseg; int Mtot; int N; int Ktot; };

#define GBN 128
#define GKC 32

__global__ __launch_bounds__(128) void gemm_splitk(GemmA a, float* __restrict__ part) {
  __shared__ float Xs[96][GKC + 4];
  __shared__ float Ws[GBN][GKC + 4];
  const int tid = threadIdx.x;
  const int n0 = blockIdx.x * GBN;
  const int s = blockIdx.y;
  const int m0 = blockIdx.z * 96;
  const int S = gridDim.y;
  const int ck = (a.Ktot + S - 1) / S;
  const int ks = s * ck;
  const int ke = (a.Ktot < ks + ck) ? a.Ktot : (ks + ck);
  float acc[12][8];
#pragma unroll
  for (int r = 0; r < 12; ++r)
#pragma unroll
    for (int c = 0; c < 8; ++c) acc[r][c] = 0.f;
  const int tx = tid & 15, ty = tid >> 4;
  int segbase = 0;
  for (int sg = 0; sg < a.nseg; ++sg) {
    Seg sge = a.seg[sg];
    int lo = ks - segbase; if (lo < 0) lo = 0;
    int hi = ke - segbase; if (hi > sge.klen) hi = sge.klen;
    for (int k0 = lo; k0 < hi; k0 += GKC) {
      // host guarantees: all split/segment boundaries are multiples of GKC=32,
      // so every chunk is full-width (kc==32) and float4 loads stay in range.
      __syncthreads();
      // X tile: 96 rows x 8 float4 col-chunks (6 loads/thread, independent)
      for (int i = tid; i < 96 * 8; i += 128) {
        int m = i >> 3, q = (i & 7) << 2;
        int mg = m0 + m;
        float4 v = {0.f, 0.f, 0.f, 0.f};
        if (mg < a.Mtot) v = *(const float4*)&sge.X[(size_t)mg * sge.ldx + k0 + q];
        *(float4*)&Xs[m][q] = v;
      }
      // W tile: 128 rows x 8 float4 col-chunks (8 loads/thread, independent)
      for (int i = tid; i < GBN * 8; i += 128) {
        int n = i >> 3, q = (i & 7) << 2;
        int ng = n0 + n;
        float4 v = {0.f, 0.f, 0.f, 0.f};
        if (ng < a.N) v = *(const float4*)&sge.W[(size_t)ng * sge.ldw + sge.koff + k0 + q];
        *(float4*)&Ws[n][q] = v;
      }
      __syncthreads();
#pragma unroll
      for (int kq = 0; kq < GKC; kq += 4) {
        float4 xv[12];
#pragma unroll
        for (int r = 0; r < 12; ++r) xv[r] = *(const float4*)&Xs[ty * 12 + r][kq];
#pragma unroll
        for (int c = 0; c < 8; ++c) {
          float4 wv = *(const float4*)&Ws[tx + 16 * c][kq];
#pragma unroll
          for (int r = 0; r < 12; ++r) {
            acc[r][c] += xv[r].x * wv.x;
            acc[r][c] += xv[r].y * wv.y;
            acc[r][c] += xv[r].z * wv.z;
            acc[r][c] += xv[r].w * wv.w;
          }
        }
      }
    }
    segbase += sge.klen;
  }
#pragma unroll
  for (int r = 0; r < 12; ++r) {
    int mg = m0 + ty * 12 + r;
    if (mg >= a.Mtot) continue;
#pragma unroll
    for (int c = 0; c < 8; ++c) {
      int ng = n0 + tx + 16 * c;
      if (ng < a.N) part[((size_t)s * a.Mtot + mg) * a.N + ng] = acc[r][c];
    }
  }
}

// ---------------- small kernels ----------------
__global__ void init_kernel(float* h1s, float* c1s, float* h2s, float* c2s,
                            int* tok, float* lpt, int* fin, int* trj) {
  int idx = blockIdx.x * 256 + threadIdx.x;
  if (idx < ROWS * HH) { h1s[idx] = 0.f; c1s[idx] = 0.f; h2s[idx] = 0.f; c2s[idx] = 0.f; }
  if (idx < ROWS) { tok[idx] = 1; lpt[idx] = 0.f; fin[idx] = 0; }
  if (idx < ROWS * TT) trj[idx] = 0;
}

__global__ void vmean_kernel(const float* __restrict__ features, float* __restrict__ vme) {
  int idx = blockIdx.x * 256 + threadIdx.x;
  if (idx >= BB * VD) return;
  int b = idx / VD, d = idx - b * VD;
  float sum = 0.f;
  for (int r = 0; r < RR; ++r) sum += features[((size_t)b * RR + r) * VD + d];
  vme[idx] = sum / (float)RR;
}

__global__ void reduce_bias_kernel(float* __restrict__ out, const float* __restrict__ parts,
                                   const float* __restrict__ bias, int rows, int cols, int S) {
  int idx = blockIdx.x * 256 + threadIdx.x;
  if (idx >= rows * cols) return;
  int c = idx % cols;
  float acc = bias[c];
  for (int s = 0; s < S; ++s) acc += parts[(size_t)s * rows * cols + idx];
  out[idx] = acc;
}

__global__ void embed_kernel(const int* __restrict__ tok, const float* __restrict__ E,
                             float* __restrict__ emb) {
  int idx = blockIdx.x * 256 + threadIdx.x;
  if (idx >= ROWS * ED) return;
  int row = idx >> 9, e2 = idx & (ED - 1);
  emb[idx] = E[(size_t)tok[row] * ED + e2];
}

__global__ void lstm_kernel(const float* __restrict__ gP, int S,
                            const float* __restrict__ bias_col, const float* __restrict__ bias_row,
                            const float* __restrict__ c_in, float* __restrict__ h_out,
                            float* __restrict__ c_out) {
  int idx = blockIdx.x * 256 + threadIdx.x;
  if (idx >= ROWS * HH) return;
  int row = idx >> 10, j = idx & (HH - 1);
  int b = row / KB;
  float g[4];
#pragma unroll
  for (int gi = 0; gi < 4; ++gi) {
    float acc = bias_col ? bias_col[gi * HH + j] : bias_row[(size_t)b * 4 * HH + gi * HH + j];
    for (int s = 0; s < S; ++s) acc += gP[((size_t)s * ROWS + row) * (4 * HH) + gi * HH + j];
    g[gi] = acc;
  }
  float ig = 1.f / (1.f + expf(-g[0]));
  float fg = 1.f / (1.f + expf(-g[1]));
  float gg = tanhf(g[2]);
  float og = 1.f / (1.f + expf(-g[3]));
  float c = fg * c_in[idx] + ig * gg;
  h_out[idx] = og * tanhf(c);
  c_out[idx] = c;
}

__global__ __launch_bounds__(256) void attn_kernel(const float* __restrict__ hpP, int S,
    const float* __restrict__ bha, const float* __restrict__ featP,
    const float* __restrict__ features, const float* __restrict__ wa,
    float* __restrict__ vhat) {
  int row = blockIdx.x;
  int b = row / KB;
  int tid = threadIdx.x;
  __shared__ float hp[PH_];
  __shared__ float e[RR];
  {
    float v = bha[tid];
    for (int s = 0; s < S; ++s) v += hpP[((size_t)s * ROWS + row) * PH_ + tid];
    hp[tid] = v;
  }
  __syncthreads();
  int wv = tid >> 6, ln = tid & 63;
  for (int r = wv * 9; r < wv * 9 + 9; ++r) {
    float p = 0.f;
#pragma unroll
    for (int i = 0; i < 4; ++i) {
      int ph = ln * 4 + i;
      p += tanhf(featP[((size_t)b * RR + r) * PH_ + ph] + hp[ph]) * wa[ph];
    }
#pragma unroll
    for (int o = 32; o; o >>= 1) p += __shfl_down(p, o);
    if (ln == 0) e[r] = p;
  }
  __syncthreads();
  if (tid == 0) {
    float m = e[0];
    for (int r = 1; r < RR; ++r) m = fmaxf(m, e[r]);
    float se = 0.f;
    for (int r = 0; r < RR; ++r) se += expf(e[r] - m);
    for (int r = 0; r < RR; ++r) e[r] = expf(e[r] - m) / se;
  }
  __syncthreads();
  for (int d = tid; d < VD; d += 256) {
    float acc2 = 0.f;
    for (int r = 0; r < RR; ++r) acc2 += e[r] * features[((size_t)b * RR + r) * VD + d];
    vhat[(size_t)row * VD + d] = acc2;
  }
}

__device__ inline float wred_max(float v) {
#pragma unroll
  for (int o = 32; o; o >>= 1) v = fmaxf(v, __shfl_down(v, o));
  return v;
}
__device__ inline float wred_sum(float v) {
#pragma unroll
  for (int o = 32; o; o >>= 1) v += __shfl_down(v, o);
  return v;
}

__global__ __launch_bounds__(256) void logsm_kernel(const float* __restrict__ lP, int S,
    const float* __restrict__ bout, float* __restrict__ logits) {
  int row = blockIdx.x, tid = threadIdx.x;
  __shared__ float red[4];
  float m = -3.4e38f;
  for (int v = tid; v < VV; v += 256) {
    float acc = bout[v];
    for (int s = 0; s < S; ++s) acc += lP[((size_t)s * ROWS + row) * VV + v];
    logits[(size_t)row * VV + v] = acc;
    m = fmaxf(m, acc);
  }
  m = wred_max(m);
  if ((tid & 63) == 0) red[tid >> 6] = m;
  __syncthreads();
  m = fmaxf(fmaxf(red[0], red[1]), fmaxf(red[2], red[3]));
  __syncthreads();
  float se = 0.f;
  for (int v = tid; v < VV; v += 256) se += expf(logits[(size_t)row * VV + v] - m);
  se = wred_sum(se);
  if ((tid & 63) == 0) red[tid >> 6] = se;
  __syncthreads();
  se = red[0] + red[1] + red[2] + red[3];
  float l = logf(se);
  for (int v = tid; v < VV; v += 256) {
    size_t ix = (size_t)row * VV + v;
    logits[ix] = (logits[ix] - m) - l;
  }
}

__device__ inline bool better(float va, int ia, float vb, int ib) {
  if (va != vb) return va > vb;
  return (unsigned)ia < (unsigned)ib;
}

__global__ __launch_bounds__(256) void topk_kernel(const float* __restrict__ logp,
    const int* __restrict__ tok_old, const float* __restrict__ lpt_old,
    const int* __restrict__ fin_old, const int* __restrict__ trj_old, int t,
    int* __restrict__ tok_new, float* __restrict__ lpt_new, int* __restrict__ fin_new,
    int* __restrict__ trj_new, int* __restrict__ parent) {
  int b = blockIdx.x, tid = threadIdx.x;
  float lv[3] = {-INFINITY, -INFINITY, -INFINITY};
  int li[3] = {-1, -1, -1};
  float lpt_k[KB]; int fin_k[KB]; int tokp[KB];
#pragma unroll
  for (int k = 0; k < KB; ++k) {
    lpt_k[k] = lpt_old[b * KB + k];
    fin_k[k] = fin_old[b * KB + k];
    tokp[k] = tok_old[b * KB + k];
  }
  for (int i = tid; i < KB * VV; i += 256) {
    int k = i / VV, v = i - k * VV;
    if (t == 0 && k > 0) break;
    float sc;
    if (fin_k[k]) {
      if (v != EOS_TOK) continue;
      sc = lpt_k[k];
    } else {
      float lg = logp[((size_t)(b * KB + k)) * VV + v];
      if (t > 0 && v == tokp[k]) lg -= 1e4f;
      sc = lpt_k[k] + lg;
    }
    if (better(sc, i, lv[2], li[2])) {
      if (better(sc, i, lv[1], li[1])) {
        lv[2] = lv[1]; li[2] = li[1];
        if (better(sc, i, lv[0], li[0])) { lv[1] = lv[0]; li[1] = li[0]; lv[0] = sc; li[0] = i; }
        else { lv[1] = sc; li[1] = i; }
      } else { lv[2] = sc; li[2] = i; }
    }
  }
  __shared__ float sv[256 * 3];
  __shared__ int si[256 * 3];
  sv[tid * 3 + 0] = lv[0]; sv[tid * 3 + 1] = lv[1]; sv[tid * 3 + 2] = lv[2];
  si[tid * 3 + 0] = li[0]; si[tid * 3 + 1] = li[1]; si[tid * 3 + 2] = li[2];
  for (int off = 128; off >= 1; off >>= 1) {
    __syncthreads();
    if (tid < off) {
      float av[3], bv2[3]; int ai3[3], bi3[3];
#pragma unroll
      for (int j = 0; j < 3; ++j) {
        av[j] = sv[tid * 3 + j]; ai3[j] = si[tid * 3 + j];
        bv2[j] = sv[(tid + off) * 3 + j]; bi3[j] = si[(tid + off) * 3 + j];
      }
      float mv[3]; int mi[3];
      int ai = 0, bi = 0;
#pragma unroll
      for (int o = 0; o < 3; ++o) {
        if (better(av[ai], ai3[ai], bv2[bi], bi3[bi])) { mv[o] = av[ai]; mi[o] = ai3[ai]; ++ai; }
        else { mv[o] = bv2[bi]; mi[o] = bi3[bi]; ++bi; }
      }
#pragma unroll
      for (int j = 0; j < 3; ++j) { sv[tid * 3 + j] = mv[j]; si[tid * 3 + j] = mi[j]; }
    }
  }
  __syncthreads();
  if (tid < KB) {
    float val = sv[tid];
    int idx = si[tid];
    int p = idx / VV, tk = idx - p * VV;
    parent[b * KB + tid] = p;
    tok_new[b * KB + tid] = tk;
    lpt_new[b * KB + tid] = val;
    fin_new[b * KB + tid] = fin_k[p] | (tk == EOS_TOK);
    for (int tt = 0; tt < TT; ++tt)
      trj_new[(b * KB + tid) * TT + tt] = (tt == t) ? tk : trj_old[(b * KB + p) * TT + tt];
  }
}

__global__ void gather_kernel(const int* __restrict__ parent,
    const float* __restrict__ h1p, const float* __restrict__ c1p,
    const float* __restrict__ h2p, const float* __restrict__ c2p,
    float* __restrict__ h1s, float* __restrict__ c1s,
    float* __restrict__ h2s, float* __restrict__ c2s) {
  int idx = blockIdx.x * 256 + threadIdx.x;
  if (idx >= ROWS * HH) return;
  int row = idx >> 10, j = idx & (HH - 1);
  int b = row / KB;
  int p = parent[row];
  size_t src = ((size_t)(b * KB + p) << 10) + j;
  h1s[idx] = h1p[src]; c1s[idx] = c1p[src];
  h2s[idx] = h2p[src]; c2s[idx] = c2p[src];
}

__global__ void out_kernel(const int* __restrict__ trj, const float* __restrict__ lpt,
                           float* __restrict__ out) {
  int idx = blockIdx.x * 256 + threadIdx.x;
  if (idx < BB * TT * KB) {
    int k = idx % KB;
    int rest = idx / KB;
    int t = rest % TT;
    int b = rest / TT;
    out[idx] = (float)trj[((size_t)(b * KB + k)) * TT + t];
  }
  if (idx < ROWS) out[BB * TT * KB + idx] = lpt[idx];
}

// ---------------- host ----------------
extern "C" void kernel_launch(void* const* d_in, const int* in_sizes, int n_in,
                              void* d_out, int out_size, void* d_ws, size_t ws_size,
                              hipStream_t stream) {
  const float* features = (const float*)d_in[0];
  const float* E = (const float*)d_in[1];
  const float* Wi1 = (const float*)d_in[2];
  const float* Wh1 = (const float*)d_in[3];
  const float* b1 = (const float*)d_in[4];
  const float* Wi2 = (const float*)d_in[5];
  const float* Wh2 = (const float*)d_in[6];
  const float* b2 = (const float*)d_in[7];
  const float* Wva = (const float*)d_in[8];
  const float* bva = (const float*)d_in[9];
  const float* Wha = (const float*)d_in[10];
  const float* bha = (const float*)d_in[11];
  const float* wa = (const float*)d_in[12];
  const float* Wout = (const float*)d_in[13];
  const float* bout = (const float*)d_in[14];
  float* out = (float*)d_out;

  const int SF = 4, SV2 = 4, SG = 16, SH = 16, SL = 8;
  float* base = (float*)d_ws;
  size_t off = 0;
  auto A = [&](size_t n) { float* p = base + off; off += n; return p; };
  float* featP = A((size_t)BB * RR * PH_);
  float* vme = A((size_t)BB * VD);
  float* gv1 = A((size_t)BB * 4 * HH);
  float* emb96 = A((size_t)ROWS * ED);
  float* vhat = A((size_t)ROWS * VD);
  float* logits = A((size_t)ROWS * VV);
  float* h1s = A((size_t)ROWS * HH);
  float* c1s = A((size_t)ROWS * HH);
  float* h2s = A((size_t)ROWS * HH);
  float* c2s = A((size_t)ROWS * HH);
  float* h1p = A((size_t)ROWS * HH);
  float* c1p = A((size_t)ROWS * HH);
  float* h2p = A((size_t)ROWS * HH);
  float* c2p = A((size_t)ROWS * HH);
  float* pF = A((size_t)SF * BB * RR * PH_);
  float* pV = A((size_t)SV2 * BB * 4 * HH);
  float* pG = A((size_t)SG * ROWS * 4 * HH);
  float* pH = A((size_t)SH * ROWS * PH_);
  float* pL = A((size_t)SL * ROWS * VV);
  float* lptA = A(ROWS);
  float* lptB = A(ROWS);
  int* ip = (int*)(base + off);
  int* tokA = ip; ip += ROWS;
  int* tokB = ip; ip += ROWS;
  int* finA = ip; ip += ROWS;
  int* finB = ip; ip += ROWS;
  int* par = ip; ip += ROWS;
  int* trjA = ip; ip += ROWS * TT;
  int* trjB = ip; ip += ROWS * TT;

  init_kernel<<<(ROWS * HH + 255) / 256, 256, 0, stream>>>(h1s, c1s, h2s, c2s, tokA, lptA, finA, trjA);
  vmean_kernel<<<(BB * VD + 255) / 256, 256, 0, stream>>>(features, vme);
  {
    GemmA a{};
    a.seg[0] = Seg{features, Wva, VD, VD, 0, VD};
    a.nseg = 1; a.Mtot = BB * RR; a.N = PH_; a.Ktot = VD;
    dim3 g((PH_ + GBN - 1) / GBN, SF, (BB * RR + 95) / 96);
    gemm_splitk<<<g, 128, 0, stream>>>(a, pF);
    reduce_bias_kernel<<<(BB * RR * PH_ + 255) / 256, 256, 0, stream>>>(featP, pF, bva, BB * RR, PH_, SF);
  }
  {
    GemmA a{};
    a.seg[0] = Seg{vme, Wi1, VD, 3584, 1024, VD};
    a.nseg = 1; a.Mtot = BB; a.N = 4 * HH; a.Ktot = VD;
    dim3 g((4 * HH + GBN - 1) / GBN, SV2, 1);
    gemm_splitk<<<g, 128, 0, stream>>>(a, pV);
    reduce_bias_kernel<<<(BB * 4 * HH + 255) / 256, 256, 0, stream>>>(gv1, pV, b1, BB, 4 * HH, SV2);
  }

  int *tokC = tokA, *tokN = tokB, *finC = finA, *finN = finB, *trjC = trjA, *trjN = trjB;
  float *lptC = lptA, *lptN = lptB;
  for (int t = 0; t < TT; ++t) {
    embed_kernel<<<(ROWS * ED + 255) / 256, 256, 0, stream>>>(tokC, E, emb96);
    {
      GemmA a{};
      a.seg[0] = Seg{h2s, Wi1, HH, 3584, 0, HH};
      a.seg[1] = Seg{emb96, Wi1, ED, 3584, 3072, ED};
      a.seg[2] = Seg{h1s, Wh1, HH, HH, 0, HH};
      a.nseg = 3; a.Mtot = ROWS; a.N = 4 * HH; a.Ktot = HH + ED + HH;
      dim3 g(32, SG, 1);
      gemm_splitk<<<g, 128, 0, stream>>>(a, pG);
    }
    lstm_kernel<<<(ROWS * HH + 255) / 256, 256, 0, stream>>>(pG, SG, nullptr, gv1, c1s, h1p, c1p);
    {
      GemmA a{};
      a.seg[0] = Seg{h1p, Wha, HH, HH, 0, HH};
      a.nseg = 1; a.Mtot = ROWS; a.N = PH_; a.Ktot = HH;
      dim3 g((PH_ + GBN - 1) / GBN, SH, 1);
      gemm_splitk<<<g, 128, 0, stream>>>(a, pH);
    }
    attn_kernel<<<ROWS, 256, 0, stream>>>(pH, SH, bha, featP, features, wa, vhat);
    {
      GemmA a{};
      a.seg[0] = Seg{h1p, Wi2, HH, 3072, 0, HH};
      a.seg[1] = Seg{vhat, Wi2, VD, 3072, 1024, VD};
      a.seg[2] = Seg{h2s, Wh2, HH, HH, 0, HH};
      a.nseg = 3; a.Mtot = ROWS; a.N = 4 * HH; a.Ktot = HH + VD + HH;
      dim3 g(32, SG, 1);
      gemm_splitk<<<g, 128, 0, stream>>>(a, pG);
    }
    lstm_kernel<<<(ROWS * HH + 255) / 256, 256, 0, stream>>>(pG, SG, b2, nullptr, c2s, h2p, c2p);
    {
      GemmA a{};
      a.seg[0] = Seg{h2p, Wout, HH, HH, 0, HH};
      a.nseg = 1; a.Mtot = ROWS; a.N = VV; a.Ktot = HH;
      dim3 g((VV + GBN - 1) / GBN, SL, 1);
      gemm_splitk<<<g, 128, 0, stream>>>(a, pL);
    }
    logsm_kernel<<<ROWS, 256, 0, stream>>>(pL, SL, bout, logits);
    topk_kernel<<<BB, 256, 0, stream>>>(logits, tokC, lptC, finC, trjC, t,
                                        tokN, lptN, finN, trjN, par);
    gather_kernel<<<(ROWS * HH + 255) / 256, 256, 0, stream>>>(par, h1p, c1p, h2p, c2p,
                                                               h1s, c1s, h2s, c2s);
    { int* tmp; float* tf;
      tmp = tokC; tokC = tokN; tokN = tmp;
      tmp = finC; finC = finN; finN = tmp;
      tmp = trjC; trjC = trjN; trjN = tmp;
      tf = lptC; lptC = lptN; lptN = tf; }
  }
  out_kernel<<<(BB * TT * KB + 255) / 256, 256, 0, stream>>>(trjC, lptC, out);
}